// Round 1
// baseline (235.385 us; speedup 1.0000x reference)
//
#include <hip/hip_runtime.h>
#include <math.h>

// Regional Interaction Module — fully fused per-pixel kernel.
// img: [32,3,512,512] f32, mask: [32,1,512,512] f32, out: [32,3,512,512] f32.
// Layout: channel-planar, HW = 512*512 = 262144 contiguous per (b,c) plane.

#define HW_SHIFT 18              // HW = 1<<18
#define HWQ_SHIFT 16             // HW/4 (float4 units)

__device__ __forceinline__ float sigm(float x) {
    // 1 / (1 + exp(-x)) via fast exp + v_rcp_f32
    return __builtin_amdgcn_rcpf(1.0f + __expf(-x));
}

__global__ __launch_bounds__(256) void rim_kernel(
    const float* __restrict__ img,  const float* __restrict__ mask,
    const float* __restrict__ qiw,  const float* __restrict__ qib,
    const float* __restrict__ kiw,  const float* __restrict__ kib,
    const float* __restrict__ viw,  const float* __restrict__ vib,
    const float* __restrict__ qrw,  const float* __restrict__ qrb,
    const float* __restrict__ krw,  const float* __restrict__ krb,
    const float* __restrict__ vrw,  const float* __restrict__ vrb,
    const float* __restrict__ fuw,  const float* __restrict__ fub,
    float* __restrict__ out)
{
    const int HWQ = 1 << HWQ_SHIFT;         // float4 groups per plane
    const int n4  = 32 * HWQ;               // total float4 groups (b,hw)

    // ---- uniform weight loads (hoisted to SGPRs by the compiler) ----
    const float w_qi0 = qiw[0], w_qi1 = qiw[1], w_qi2 = qiw[2], b_qi = qib[0];
    const float w_ki0 = kiw[0], w_ki1 = kiw[1], w_ki2 = kiw[2], b_ki = kib[0];
    float w_vi[9], b_vi[3];
#pragma unroll
    for (int j = 0; j < 9; ++j) w_vi[j] = viw[j];
#pragma unroll
    for (int j = 0; j < 3; ++j) b_vi[j] = vib[j];
    const float w_qr = qrw[0], b_qr = qrb[0];
    const float w_kr = krw[0], b_kr = krb[0];
    const float w_vr = vrw[0], b_vr = vrb[0];
    float w_fu[18], b_fu[3];
#pragma unroll
    for (int j = 0; j < 18; ++j) w_fu[j] = fuw[j];
#pragma unroll
    for (int j = 0; j < 3; ++j) b_fu[j] = fub[j];

    const int tid    = blockIdx.x * blockDim.x + threadIdx.x;
    const int stride = gridDim.x * blockDim.x;

    for (int i = tid; i < n4; i += stride) {
        const int b   = i >> HWQ_SHIFT;           // batch
        const int hw4 = i & (HWQ - 1);            // float4 index within plane

        const float4* ip = (const float4*)(img  + ((size_t)b * 3 << HW_SHIFT)) + hw4;
        const float4* mp = (const float4*)(mask + ((size_t)b     << HW_SHIFT)) + hw4;
        float4 x0 = ip[0];
        float4 x1 = ip[HWQ];
        float4 x2 = ip[2 * HWQ];
        float4 mm = mp[0];

        float4 o0, o1, o2;
        float* px0 = &x0.x; float* px1 = &x1.x; float* px2 = &x2.x;
        float* pm  = &mm.x;
        float* po0 = &o0.x; float* po1 = &o1.x; float* po2 = &o2.x;

#pragma unroll
        for (int l = 0; l < 4; ++l) {
            const float X0 = px0[l], X1 = px1[l], X2 = px2[l], M = pm[l];

            const float q_i = b_qi + w_qi0 * X0 + w_qi1 * X1 + w_qi2 * X2;
            const float k_i = b_ki + w_ki0 * X0 + w_ki1 * X1 + w_ki2 * X2;
            const float v0  = b_vi[0] + w_vi[0] * X0 + w_vi[1] * X1 + w_vi[2] * X2;
            const float v1  = b_vi[1] + w_vi[3] * X0 + w_vi[4] * X1 + w_vi[5] * X2;
            const float v2  = b_vi[2] + w_vi[6] * X0 + w_vi[7] * X1 + w_vi[8] * X2;
            const float q_r = b_qr + w_qr * M;
            const float k_r = b_kr + w_kr * M;
            const float v_r = b_vr + w_vr * M;

            const float s_ii = sigm(q_i * k_i);
            const float s_ir = sigm(q_i * k_r);
            const float s_rr = sigm(q_r * k_r);
            const float s_ri = sigm(q_r * k_i);

            const float fi0 = s_ii * v0 + s_ir * v_r;
            const float fi1 = s_ii * v1 + s_ir * v_r;
            const float fi2 = s_ii * v2 + s_ir * v_r;
            const float fr0 = s_rr * v_r + s_ri * v0;
            const float fr1 = s_rr * v_r + s_ri * v1;
            const float fr2 = s_rr * v_r + s_ri * v2;

            po0[l] = b_fu[0] + w_fu[0]  * fi0 + w_fu[1]  * fi1 + w_fu[2]  * fi2
                             + w_fu[3]  * fr0 + w_fu[4]  * fr1 + w_fu[5]  * fr2;
            po1[l] = b_fu[1] + w_fu[6]  * fi0 + w_fu[7]  * fi1 + w_fu[8]  * fi2
                             + w_fu[9]  * fr0 + w_fu[10] * fr1 + w_fu[11] * fr2;
            po2[l] = b_fu[2] + w_fu[12] * fi0 + w_fu[13] * fi1 + w_fu[14] * fi2
                             + w_fu[15] * fr0 + w_fu[16] * fr1 + w_fu[17] * fr2;
        }

        float4* op = (float4*)(out + ((size_t)b * 3 << HW_SHIFT)) + hw4;
        op[0]       = o0;
        op[HWQ]     = o1;
        op[2 * HWQ] = o2;
    }
}

extern "C" void kernel_launch(void* const* d_in, const int* in_sizes, int n_in,
                              void* d_out, int out_size, void* d_ws, size_t ws_size,
                              hipStream_t stream) {
    const float* img  = (const float*)d_in[0];
    const float* mask = (const float*)d_in[1];
    const float* qiw  = (const float*)d_in[2];
    const float* qib  = (const float*)d_in[3];
    const float* kiw  = (const float*)d_in[4];
    const float* kib  = (const float*)d_in[5];
    const float* viw  = (const float*)d_in[6];
    const float* vib  = (const float*)d_in[7];
    const float* qrw  = (const float*)d_in[8];
    const float* qrb  = (const float*)d_in[9];
    const float* krw  = (const float*)d_in[10];
    const float* krb  = (const float*)d_in[11];
    const float* vrw  = (const float*)d_in[12];
    const float* vrb  = (const float*)d_in[13];
    const float* fuw  = (const float*)d_in[14];
    const float* fub  = (const float*)d_in[15];
    float* out = (float*)d_out;

    // 2048 blocks x 256 threads: 524288 threads, 4 float4-iters each.
    rim_kernel<<<2048, 256, 0, stream>>>(img, mask, qiw, qib, kiw, kib, viw, vib,
                                         qrw, qrb, krw, krb, vrw, vrb, fuw, fub, out);
}

// Round 3
// 232.806 us; speedup vs baseline: 1.0111x; 1.0111x over previous
//
#include <hip/hip_runtime.h>
#include <math.h>

// Regional Interaction Module — fully fused per-pixel kernel, round 3.
// img: [32,3,512,512] f32, mask: [32,1,512,512] f32, out: [32,3,512,512] f32.
// Round-2/3 changes vs round 1:
//  - exact-fit grid, 2 float4-groups per thread, ALL 8 loads issued upfront
//    (no grid-stride back-edge serializing memory issue)
//  - nontemporal stores for out (don't let the 100MB output write-allocate
//    evict input lines from the 256MB LLC). Round-3 fix: use a native clang
//    ext_vector type for the builtin (HIP_vector_type rejected).

#define HW_SHIFT  18             // HW = 512*512 = 1<<18 floats per plane
#define HWQ_SHIFT 16             // HW/4 float4 groups per plane
#define HWQ (1 << HWQ_SHIFT)

typedef float vfloat4 __attribute__((ext_vector_type(4)));

__device__ __forceinline__ float sigm(float x) {
    return __builtin_amdgcn_rcpf(1.0f + __expf(-x));
}

__device__ __forceinline__ void nt_store4(float4 v, float* p) {
    vfloat4 w = {v.x, v.y, v.z, v.w};
    __builtin_nontemporal_store(w, (vfloat4*)p);
}

__global__ __launch_bounds__(256) void rim_kernel(
    const float* __restrict__ img,  const float* __restrict__ mask,
    const float* __restrict__ qiw,  const float* __restrict__ qib,
    const float* __restrict__ kiw,  const float* __restrict__ kib,
    const float* __restrict__ viw,  const float* __restrict__ vib,
    const float* __restrict__ qrw,  const float* __restrict__ qrb,
    const float* __restrict__ krw,  const float* __restrict__ krb,
    const float* __restrict__ vrw,  const float* __restrict__ vrb,
    const float* __restrict__ fuw,  const float* __restrict__ fub,
    float* __restrict__ out)
{
    // ---- uniform weight loads (scalar loads -> SGPRs) ----
    const float w_qi0 = qiw[0], w_qi1 = qiw[1], w_qi2 = qiw[2], b_qi = qib[0];
    const float w_ki0 = kiw[0], w_ki1 = kiw[1], w_ki2 = kiw[2], b_ki = kib[0];
    float w_vi[9], b_vi[3];
#pragma unroll
    for (int j = 0; j < 9; ++j) w_vi[j] = viw[j];
#pragma unroll
    for (int j = 0; j < 3; ++j) b_vi[j] = vib[j];
    const float w_qr = qrw[0], b_qr = qrb[0];
    const float w_kr = krw[0], b_kr = krb[0];
    const float w_vr = vrw[0], b_vr = vrb[0];
    float w_fu[18], b_fu[3];
#pragma unroll
    for (int j = 0; j < 18; ++j) w_fu[j] = fuw[j];
#pragma unroll
    for (int j = 0; j < 3; ++j) b_fu[j] = fub[j];

    // Block covers 512 consecutive float4 groups; 512 | 65536 so the whole
    // block (both halves) lives in one batch plane.
    const int g0  = blockIdx.x * 512 + threadIdx.x;   // first group
    const int b   = g0 >> HWQ_SHIFT;                  // batch (wave-uniform)
    const int hw0 = g0 & (HWQ - 1);
    const int hw1 = hw0 + 256;

    const float4* ip = (const float4*)(img  + ((size_t)b * 3 << HW_SHIFT));
    const float4* mp = (const float4*)(mask + ((size_t)b     << HW_SHIFT));

    // ---- all 8 loads upfront: 128B per thread in flight ----
    float4 xa0 = ip[hw0];
    float4 xa1 = ip[hw0 + HWQ];
    float4 xa2 = ip[hw0 + 2 * HWQ];
    float4 mqa = mp[hw0];
    float4 xb0 = ip[hw1];
    float4 xb1 = ip[hw1 + HWQ];
    float4 xb2 = ip[hw1 + 2 * HWQ];
    float4 mqb = mp[hw1];

    auto compute = [&](const float4& X0q, const float4& X1q, const float4& X2q,
                       const float4& Mq, float4& O0, float4& O1, float4& O2) {
        const float* px0 = &X0q.x; const float* px1 = &X1q.x;
        const float* px2 = &X2q.x; const float* pm  = &Mq.x;
        float* po0 = &O0.x; float* po1 = &O1.x; float* po2 = &O2.x;
#pragma unroll
        for (int l = 0; l < 4; ++l) {
            const float X0 = px0[l], X1 = px1[l], X2 = px2[l], M = pm[l];

            const float q_i = b_qi + w_qi0 * X0 + w_qi1 * X1 + w_qi2 * X2;
            const float k_i = b_ki + w_ki0 * X0 + w_ki1 * X1 + w_ki2 * X2;
            const float v0  = b_vi[0] + w_vi[0] * X0 + w_vi[1] * X1 + w_vi[2] * X2;
            const float v1  = b_vi[1] + w_vi[3] * X0 + w_vi[4] * X1 + w_vi[5] * X2;
            const float v2  = b_vi[2] + w_vi[6] * X0 + w_vi[7] * X1 + w_vi[8] * X2;
            const float q_r = b_qr + w_qr * M;
            const float k_r = b_kr + w_kr * M;
            const float v_r = b_vr + w_vr * M;

            const float s_ii = sigm(q_i * k_i);
            const float s_ir = sigm(q_i * k_r);
            const float s_rr = sigm(q_r * k_r);
            const float s_ri = sigm(q_r * k_i);

            const float fi0 = s_ii * v0 + s_ir * v_r;
            const float fi1 = s_ii * v1 + s_ir * v_r;
            const float fi2 = s_ii * v2 + s_ir * v_r;
            const float fr0 = s_rr * v_r + s_ri * v0;
            const float fr1 = s_rr * v_r + s_ri * v1;
            const float fr2 = s_rr * v_r + s_ri * v2;

            po0[l] = b_fu[0] + w_fu[0]  * fi0 + w_fu[1]  * fi1 + w_fu[2]  * fi2
                             + w_fu[3]  * fr0 + w_fu[4]  * fr1 + w_fu[5]  * fr2;
            po1[l] = b_fu[1] + w_fu[6]  * fi0 + w_fu[7]  * fi1 + w_fu[8]  * fi2
                             + w_fu[9]  * fr0 + w_fu[10] * fr1 + w_fu[11] * fr2;
            po2[l] = b_fu[2] + w_fu[12] * fi0 + w_fu[13] * fi1 + w_fu[14] * fi2
                             + w_fu[15] * fr0 + w_fu[16] * fr1 + w_fu[17] * fr2;
        }
    };

    float* op = out + ((size_t)b * 3 << HW_SHIFT);

    float4 o0, o1, o2;
    compute(xa0, xa1, xa2, mqa, o0, o1, o2);
    nt_store4(o0, op + 4 * hw0);
    nt_store4(o1, op + 4 * (hw0 + HWQ));
    nt_store4(o2, op + 4 * (hw0 + 2 * HWQ));

    compute(xb0, xb1, xb2, mqb, o0, o1, o2);
    nt_store4(o0, op + 4 * hw1);
    nt_store4(o1, op + 4 * (hw1 + HWQ));
    nt_store4(o2, op + 4 * (hw1 + 2 * HWQ));
}

extern "C" void kernel_launch(void* const* d_in, const int* in_sizes, int n_in,
                              void* d_out, int out_size, void* d_ws, size_t ws_size,
                              hipStream_t stream) {
    const float* img  = (const float*)d_in[0];
    const float* mask = (const float*)d_in[1];
    const float* qiw  = (const float*)d_in[2];
    const float* qib  = (const float*)d_in[3];
    const float* kiw  = (const float*)d_in[4];
    const float* kib  = (const float*)d_in[5];
    const float* viw  = (const float*)d_in[6];
    const float* vib  = (const float*)d_in[7];
    const float* qrw  = (const float*)d_in[8];
    const float* qrb  = (const float*)d_in[9];
    const float* krw  = (const float*)d_in[10];
    const float* krb  = (const float*)d_in[11];
    const float* vrw  = (const float*)d_in[12];
    const float* vrb  = (const float*)d_in[13];
    const float* fuw  = (const float*)d_in[14];
    const float* fub  = (const float*)d_in[15];
    float* out = (float*)d_out;

    // n4 = 32*65536 = 2,097,152 float4 groups; 2 per thread ->
    // 1,048,576 threads = 4096 blocks x 256 (exact fit, no bounds check).
    rim_kernel<<<4096, 256, 0, stream>>>(img, mask, qiw, qib, kiw, kib, viw, vib,
                                         qrw, qrb, krw, krb, vrw, vrb, fuw, fub, out);
}